// Round 15
// baseline (217.599 us; speedup 1.0000x reference)
//
#include <hip/hip_runtime.h>
#include <hip/hip_bf16.h>
#include <math.h>

#define BB 128
#define NN 2048
#define FIN 17

#define SCALE_I 1048576.0f          // 2^20 fixed-point scale
#define INV_SCALE 9.5367431640625e-07f

typedef unsigned short ushort_t;
typedef unsigned long long ull_t;
typedef __attribute__((ext_vector_type(4))) unsigned short u16x4;
typedef __attribute__((ext_vector_type(8))) short s16x8;
typedef __attribute__((ext_vector_type(4))) float f32x4;

__device__ __forceinline__ float b2f(unsigned short u) {
    unsigned int v = ((unsigned int)u) << 16;
    return __builtin_bit_cast(float, v);
}
__device__ __forceinline__ unsigned short f2b(float f) {
    __hip_bfloat16 h = __float2bfloat16(f);
    return __builtin_bit_cast(unsigned short, h);
}
// fast RNE f32->bf16 for finite values (no NaN path)
__device__ __forceinline__ unsigned short f2b_fast(float f) {
    unsigned int u = __builtin_bit_cast(unsigned int, f);
    u += 0x7FFFu + ((u >> 16) & 1u);
    return (unsigned short)(u >> 16);
}
// gelu via A&S 7.1.26 erf approx (|abs err| <= 1.5e-7)
__device__ __forceinline__ float gelu_f(float x) {
    float ax = fabsf(x) * 0.70710678118654752f;
    float t = 1.0f / (1.0f + 0.3275911f * ax);
    float poly = t * (0.254829592f +
                 t * (-0.284496736f +
                 t * (1.421413741f +
                 t * (-1.453152027f +
                 t * 1.061405429f))));
    float erfv = 1.0f - poly * __expf(-ax * ax);
    erfv = (x >= 0.f) ? erfv : -erfv;
    return 0.5f * x * (1.0f + erfv);
}
__device__ __forceinline__ float lrelu_f(float x) {
    return x >= 0.0f ? x : 0.2f * x;
}
// fixed-point quantize: EXACTLY the q20 used by the proven R13 arithmetic
__device__ __forceinline__ long long q20(float x) {
    return (long long)(x * SCALE_I);
}

// ---------------- Stage 1: x = LN(gelu(in @ W_node + b_node)) -> [Bc*N,128] bf16
// (R13 verbatim — numerics frozen)
__global__ __launch_bounds__(256) void k_fcnode(
    const float* __restrict__ X, const float* __restrict__ W,
    const float* __restrict__ bias, const float* __restrict__ g,
    const float* __restrict__ beta, ushort_t* __restrict__ out) {
    __shared__ float Ws[FIN * 128];
    __shared__ float xs[64 * FIN];
    __shared__ float bl[128], gl[128], bet[128];
    int tid = threadIdx.x;
    long long rbase = (long long)blockIdx.x * 64;
    for (int i = tid; i < FIN * 128; i += 256) Ws[i] = W[i];
    for (int i = tid; i < 64 * FIN; i += 256) xs[i] = X[rbase * FIN + i];
    if (tid < 128) {
        bl[tid] = bias[tid]; gl[tid] = g[tid]; bet[tid] = beta[tid];
    }
    __syncthreads();
    int lane32 = tid & 31, sub = tid >> 5;
    int c0 = 4 * lane32;
    f32x4 acc[8] = {};
#pragma unroll
    for (int k = 0; k < FIN; k++) {
        f32x4 w = *(const f32x4*)(Ws + k * 128 + c0);
#pragma unroll
        for (int r = 0; r < 8; r++) {
            float xv = xs[(sub + 8 * r) * FIN + k];
            acc[r][0] = fmaf(xv, w[0], acc[r][0]);
            acc[r][1] = fmaf(xv, w[1], acc[r][1]);
            acc[r][2] = fmaf(xv, w[2], acc[r][2]);
            acc[r][3] = fmaf(xv, w[3], acc[r][3]);
        }
    }
#pragma unroll
    for (int r = 0; r < 8; r++) {
        int lr = sub + 8 * r;
        float v[4], s = 0.f, sq = 0.f;
#pragma unroll
        for (int j = 0; j < 4; j++) {
            v[j] = gelu_f(acc[r][j] + bl[c0 + j]);
            s += v[j]; sq += v[j] * v[j];
        }
#pragma unroll
        for (int mk = 16; mk >= 1; mk >>= 1) {
            s += __shfl_xor(s, mk, 32); sq += __shfl_xor(sq, mk, 32);
        }
        float mean = s * (1.f / 128.f);
        float var = sq * (1.f / 128.f) - mean * mean;
        float rstd = rsqrtf(var + 1e-5f);
        u16x4 o4;
#pragma unroll
        for (int j = 0; j < 4; j++)
            o4[j] = f2b_fast((v[j] - mean) * rstd * gl[c0 + j] + bet[c0 + j]);
        *(u16x4*)(out + (rbase + lr) * 128 + c0) = o4;
    }
}

// ---------------- W fragment prep: f32 [K,96] -> bf16 hi/lo in MFMA B-lane layout
template <int K>
__global__ __launch_bounds__(256) void k_wprep(
    const float* __restrict__ W, ushort_t* __restrict__ hi, ushort_t* __restrict__ lo) {
    constexpr int S = K / 32;
    int gid = blockIdx.x * 256 + threadIdx.x;
    if (gid >= 6 * S * 64) return;
    int lane = gid & 63, f = gid >> 6;
    int t = f / S, s = f - t * S;
    int n = 16 * t + (lane & 15);
    int kbase = 32 * s + 8 * (lane >> 4);
#pragma unroll
    for (int j = 0; j < 8; j++) {
        float w = W[(kbase + j) * 96 + n];
        ushort_t h = f2b(w);
        float rem = w - b2f(h);
        hi[gid * 8 + j] = h;
        lo[gid * 8 + j] = f2b(rem);
    }
}

// ---------------- xr0[b] = X[b,0,:] @ Wr + br  -> [Bc,96] f32
template <int K>
__global__ __launch_bounds__(128) void k_xr0(
    const ushort_t* __restrict__ X, const float* __restrict__ Wr,
    const float* __restrict__ br, float* __restrict__ xr0) {
    int b = blockIdx.x, c = threadIdx.x;
    __shared__ float xs[K];
    if (threadIdx.x < K) xs[threadIdx.x] = b2f(X[(long long)b * NN * K + threadIdx.x]);
    __syncthreads();
    if (c >= 96) return;
    float acc = br[c];
    for (int k = 0; k < K; k++) acc = fmaf(xs[k], Wr[k * 96 + c], acc);
    xr0[b * 96 + c] = acc;
}

// ---------------- MFMA conv with fused attention (+pool) partials.
// Block = 256 thr = 4 waves; wave: 32 rows x 96 cols (128 rows/block).
// ONLY change vs R13 (bit-exact on output): W-hi staged in LDS, W-lo read
// from global (L2-resident; same bytes -> identical MFMA stream). LDS halves
// -> blocks/CU doubles (3->6 conv1, 4->8 conv2).
// DETERMINISTIC BY CONSTRUCTION: plain-stores of q20 int64 partials to fixed
// slots (slot = row0>>5). No atomics, no RMW.
template <int K, bool POOLF>
__global__ __launch_bounds__(256) void k_conv(
    const ushort_t* __restrict__ X,     // [Bc*N,K] bf16
    const ushort_t* __restrict__ Whi, const ushort_t* __restrict__ Wlo,
    const float* __restrict__ bl, const float* __restrict__ att,
    const float* __restrict__ xr0,      // [Bc,96]
    const float* __restrict__ bias, const float* __restrict__ lng,
    const float* __restrict__ lnb,
    long long* __restrict__ w0part,     // [Bc*64, 96] q20 sum e*xl per slot
    long long* __restrict__ zpart,      // [Bc*64, 4]  q20 sum e per head
    ushort_t* __restrict__ Xout,        // layer1: [Bc*N,96] bf16
    long long* __restrict__ pspart,     // layer2: [Bc*64, 96] q20 sum pe
    long long* __restrict__ pwpart,     // layer2: [Bc*64, 96] q20 sum pe*v
    const float* __restrict__ tptr)
{
    constexpr int S = K / 32;
    constexpr int NFRAG = 6 * S * 64;
    __shared__ s16x8 lWh[NFRAG];
    int tid = threadIdx.x;
    {
        const s16x8* gh = (const s16x8*)Whi;
        for (int i = tid; i < NFRAG; i += 256) lWh[i] = gh[i];
    }
    __syncthreads();

    int wave = tid >> 6, lane = tid & 63;
    int hi4 = lane >> 4, cl = lane & 15;
    int row0 = blockIdx.x * 128 + wave * 32;
    int b = row0 >> 11;     // chunk-local batch (NN=2048)
    int slot = row0 >> 5;   // batch b owns slots [b*64, b*64+64)

    const s16x8* gWlo = (const s16x8*)Wlo;
    f32x4 acc[2][6] = {};
#pragma unroll
    for (int s = 0; s < S; s++) {
        s16x8 a0 = *(const s16x8*)(X + (size_t)(row0 + cl) * K + s * 32 + hi4 * 8);
        s16x8 a1 = *(const s16x8*)(X + (size_t)(row0 + 16 + cl) * K + s * 32 + hi4 * 8);
#pragma unroll
        for (int t = 0; t < 6; t++) {
            s16x8 bh = lWh[(t * S + s) * 64 + lane];
            s16x8 bo = gWlo[(t * S + s) * 64 + lane];
            acc[0][t] = __builtin_amdgcn_mfma_f32_16x16x32_bf16(a0, bh, acc[0][t], 0, 0, 0);
            acc[0][t] = __builtin_amdgcn_mfma_f32_16x16x32_bf16(a0, bo, acc[0][t], 0, 0, 0);
            acc[1][t] = __builtin_amdgcn_mfma_f32_16x16x32_bf16(a1, bh, acc[1][t], 0, 0, 0);
            acc[1][t] = __builtin_amdgcn_mfma_f32_16x16x32_bf16(a1, bo, acc[1][t], 0, 0, 0);
        }
    }

    float blc[6], xrc[6], attc[6], bic[6], gc[6], bcc[6];
#pragma unroll
    for (int t = 0; t < 6; t++) {
        int c = 16 * t + cl;
        blc[t] = bl[c]; xrc[t] = xr0[b * 96 + c]; attc[t] = att[c];
        bic[t] = bias[c]; gc[t] = lng[c]; bcc[t] = lnb[c];
    }
    float tv = POOLF ? tptr[0] : 0.f;

    float w0p[6] = {0.f, 0.f, 0.f, 0.f, 0.f, 0.f};
    float zp[3] = {0.f, 0.f, 0.f};
    float psp[6] = {0.f, 0.f, 0.f, 0.f, 0.f, 0.f};
    float pwp[6] = {0.f, 0.f, 0.f, 0.f, 0.f, 0.f};

#pragma unroll
    for (int q = 0; q < 2; q++) {
#pragma unroll
        for (int i = 0; i < 4; i++) {
            int row = row0 + q * 16 + hi4 * 4 + i;
            float xl[6];
#pragma unroll
            for (int t = 0; t < 6; t++) xl[t] = acc[q][t][i] + blc[t];
            // score partials per head (pre-reduction)
            float pv[6];
#pragma unroll
            for (int t = 0; t < 6; t++) pv[t] = attc[t] * lrelu_f(xl[t] + xrc[t]);
            float p0 = pv[0] + pv[1], p1 = pv[2] + pv[3], p2 = pv[4] + pv[5];
            // output-path gelu partials (independent of scores)
            float o[6], s = 0.f, sq = 0.f;
#pragma unroll
            for (int t = 0; t < 6; t++) {
                o[t] = gelu_f(xl[t] + bic[t]);
                s += o[t]; sq += o[t] * o[t];
            }
            // single combined 4-step tree over the 16-lane cl group
#pragma unroll
            for (int mk = 1; mk <= 8; mk <<= 1) {
                p0 += __shfl_xor(p0, mk, 64);
                p1 += __shfl_xor(p1, mk, 64);
                p2 += __shfl_xor(p2, mk, 64);
                s  += __shfl_xor(s,  mk, 64);
                sq += __shfl_xor(sq, mk, 64);
            }
            float e0 = __expf(fminf(p0, 24.f));
            float e1 = __expf(fminf(p1, 24.f));
            float e2 = __expf(fminf(p2, 24.f));
            w0p[0] = fmaf(e0, xl[0], w0p[0]); w0p[1] = fmaf(e0, xl[1], w0p[1]);
            w0p[2] = fmaf(e1, xl[2], w0p[2]); w0p[3] = fmaf(e1, xl[3], w0p[3]);
            w0p[4] = fmaf(e2, xl[4], w0p[4]); w0p[5] = fmaf(e2, xl[5], w0p[5]);
            zp[0] += e0; zp[1] += e1; zp[2] += e2;
            float mean = s * (1.f / 96.f);
            float var = sq * (1.f / 96.f) - mean * mean;
            float rstd = rsqrtf(var + 1e-5f);
            if ((row & (NN - 1)) != 0) {
                if (!POOLF) {
#pragma unroll
                    for (int t = 0; t < 6; t++)
                        Xout[(size_t)row * 96 + 16 * t + cl] =
                            f2b_fast((o[t] - mean) * rstd * gc[t] + bcc[t]);
                } else {
#pragma unroll
                    for (int t = 0; t < 6; t++) {
                        float v = (o[t] - mean) * rstd * gc[t] + bcc[t];
                        float pe = __expf(fminf(tv * v, 24.f));
                        psp[t] += pe;
                        pwp[t] = fmaf(pe, v, pwp[t]);
                    }
                }
            }
        }
    }

    // reduce across the 4 hi4 groups (lanes cl, cl+16, cl+32, cl+48)
#pragma unroll
    for (int t = 0; t < 6; t++) {
        w0p[t] += __shfl_xor(w0p[t], 16, 64);
        w0p[t] += __shfl_xor(w0p[t], 32, 64);
    }
#pragma unroll
    for (int h = 0; h < 3; h++) {
        zp[h] += __shfl_xor(zp[h], 16, 64);
        zp[h] += __shfl_xor(zp[h], 32, 64);
    }
    if (POOLF) {
#pragma unroll
        for (int t = 0; t < 6; t++) {
            psp[t] += __shfl_xor(psp[t], 16, 64);
            psp[t] += __shfl_xor(psp[t], 32, 64);
            pwp[t] += __shfl_xor(pwp[t], 16, 64);
            pwp[t] += __shfl_xor(pwp[t], 32, 64);
        }
    }
    // plain stores of q20 integers to this wave's fixed slot
    if (lane < 16) {
#pragma unroll
        for (int t = 0; t < 6; t++)
            w0part[(size_t)slot * 96 + 16 * t + lane] = q20(w0p[t]);
        if (POOLF) {
#pragma unroll
            for (int t = 0; t < 6; t++) {
                pspart[(size_t)slot * 96 + 16 * t + lane] = q20(psp[t]);
                pwpart[(size_t)slot * 96 + 16 * t + lane] = q20(pwp[t]);
            }
        }
    }
    if (lane == 0) {
        zpart[slot * 4 + 0] = q20(zp[0]);
        zpart[slot * 4 + 1] = q20(zp[1]);
        zpart[slot * 4 + 2] = q20(zp[2]);
        zpart[slot * 4 + 3] = 0ll;
    }
}

// ---------------- combine slots (exact integer sums) + finalize node-0 row.
// LAYER 1: write X2 row 0 (bf16).  LAYER 2: write row-0 LN value to row0v.
template <int LAYER>
__global__ __launch_bounds__(128) void k_row0(
    const long long* __restrict__ w0part, const long long* __restrict__ zpart,
    const float* __restrict__ bias, const float* __restrict__ g,
    const float* __restrict__ beta, ushort_t* __restrict__ X2,
    float* __restrict__ row0v) {
    int b = blockIdx.x, t = threadIdx.x;
    __shared__ float vv[96];
    __shared__ float red2[2];
    __shared__ float zs[3];
    if (t < 3) {
        long long z = 0;
        for (int s = 0; s < 64; s++) z += zpart[(b * 64 + s) * 4 + t];
        zs[t] = (float)z;
    }
    long long wsum = 0;
    if (t < 96) {
        for (int s = 0; s < 64; s++)
            wsum += w0part[(size_t)(b * 64 + s) * 96 + t];
    }
    __syncthreads();
    float val = 0.f;
    if (t < 96) {
        float wf = (float)wsum;
        float zf = zs[t >> 5];
        val = gelu_f(wf / zf + bias[t]);   // fixed-point scale cancels
        vv[t] = val;
    }
    __syncthreads();
    if (t < 32) {
        float a = vv[t], b2 = vv[t + 32], c = vv[t + 64];
        float s = a + b2 + c, sq = a * a + b2 * b2 + c * c;
#pragma unroll
        for (int mk = 16; mk >= 1; mk >>= 1) { s += __shfl_xor(s, mk, 32); sq += __shfl_xor(sq, mk, 32); }
        if (t == 0) { red2[0] = s; red2[1] = sq; }
    }
    __syncthreads();
    float mean = red2[0] * (1.f / 96.f);
    float var = red2[1] * (1.f / 96.f) - mean * mean;
    float rstd = rsqrtf(var + 1e-5f);
    if (t < 96) {
        float ln = (val - mean) * rstd * g[t] + beta[t];
        if (LAYER == 1) {
            X2[(long long)b * NN * 96 + t] = f2b(ln);
        } else {
            row0v[b * 96 + t] = ln;
        }
    }
}

// ---------------- final: pool combine (exact integer sums + row-0 term)
// then out = LN(gelu(pooled @ W_out + b_out)) -> [Bc,256]
__global__ __launch_bounds__(256) void k_out(
    const long long* __restrict__ pspart, const long long* __restrict__ pwpart,
    const float* __restrict__ row0v, const float* __restrict__ tptr,
    const float* __restrict__ W, const float* __restrict__ bias,
    const float* __restrict__ g, const float* __restrict__ beta,
    float* __restrict__ out) {
    int b = blockIdx.x, c = threadIdx.x;
    __shared__ float ps[96];
    __shared__ float rs[4], rq[4];
    if (c < 96) {
        long long Si = 0, Wi = 0;
        for (int s = 0; s < 64; s++) {
            Si += pspart[(size_t)(b * 64 + s) * 96 + c];
            Wi += pwpart[(size_t)(b * 64 + s) * 96 + c];
        }
        float ln0 = row0v[b * 96 + c];
        float pe0 = __expf(fminf(tptr[0] * ln0, 24.f));
        float S = (float)Si * INV_SCALE + pe0;
        float Wp = (float)Wi * INV_SCALE + pe0 * ln0;
        ps[c] = Wp / S;
    }
    __syncthreads();
    float acc = bias[c];
    for (int k = 0; k < 96; k++) acc = fmaf(ps[k], W[k * 256 + c], acc);
    float v = gelu_f(acc);
    float s = v, sq = v * v;
#pragma unroll
    for (int mk = 32; mk >= 1; mk >>= 1) { s += __shfl_xor(s, mk, 64); sq += __shfl_xor(sq, mk, 64); }
    if ((c & 63) == 0) { rs[c >> 6] = s; rq[c >> 6] = sq; }
    __syncthreads();
    s = rs[0] + rs[1] + rs[2] + rs[3];
    sq = rq[0] + rq[1] + rq[2] + rq[3];
    float mean = s * (1.f / 256.f);
    float var = sq * (1.f / 256.f) - mean * mean;
    float rstd = rsqrtf(var + 1e-5f);
    out[b * 256 + c] = (v - mean) * rstd * g[c] + beta[c];
}

extern "C" void kernel_launch(void* const* d_in, const int* in_sizes, int n_in,
                              void* d_out, int out_size, void* d_ws, size_t ws_size,
                              hipStream_t stream) {
    const float* in0    = (const float*)d_in[0];
    const float* W_node = (const float*)d_in[1];
    const float* b_node = (const float*)d_in[2];
    const float* lnn_g  = (const float*)d_in[3];
    const float* lnn_b  = (const float*)d_in[4];
    const float* Wl1 = (const float*)d_in[5];
    const float* bl1 = (const float*)d_in[6];
    const float* Wr1 = (const float*)d_in[7];
    const float* br1 = (const float*)d_in[8];
    const float* att1 = (const float*)d_in[9];
    const float* bias1 = (const float*)d_in[10];
    const float* lnc1_g = (const float*)d_in[11];
    const float* lnc1_b = (const float*)d_in[12];
    const float* Wl2 = (const float*)d_in[13];
    const float* bl2 = (const float*)d_in[14];
    const float* Wr2 = (const float*)d_in[15];
    const float* br2 = (const float*)d_in[16];
    const float* att2 = (const float*)d_in[17];
    const float* bias2 = (const float*)d_in[18];
    const float* lnc2_g = (const float*)d_in[19];
    const float* lnc2_b = (const float*)d_in[20];
    const float* tptr = (const float*)d_in[21];
    const float* W_out = (const float*)d_in[22];
    const float* b_out = (const float*)d_in[23];
    const float* lno_g = (const float*)d_in[24];
    const float* lno_b = (const float*)d_in[25];

    auto alignup = [](size_t x) { return (x + 255) & ~(size_t)255; };

    // fixed region: MFMA B-fragments (hi/lo) for both conv layers
    const size_t wf1 = (size_t)6 * 4 * 64 * 8;  // K=128
    const size_t wf2 = (size_t)6 * 3 * 64 * 8;  // K=96
    char* base = (char*)d_ws;
    ushort_t* wf1h = (ushort_t*)base;             base += alignup(wf1 * 2);
    ushort_t* wf1l = (ushort_t*)base;             base += alignup(wf1 * 2);
    ushort_t* wf2h = (ushort_t*)base;             base += alignup(wf2 * 2);
    ushort_t* wf2l = (ushort_t*)base;             base += alignup(wf2 * 2);
    size_t fixed = (size_t)(base - (char*)d_ws);

    // per-chunk: X bf16, X2 bf16, xr0, w0part(i64), zpart(i64), row0v.
    // pool slot arrays (pspart/pwpart, i64) alias the Xbuf region (dead
    // after conv1; 2*slots*96*8 = 12.6 MB << Xbuf 67 MB at bc=128).
    auto need = [&](int bcx) -> size_t {
        size_t rn = (size_t)bcx * NN;
        size_t slots = (size_t)bcx * 64;
        return fixed
             + alignup(rn * 128 * 2)             // X bf16 (holds ps/pw i64 later)
             + alignup(rn * 96 * 2)              // X2 bf16
             + alignup((size_t)bcx * 96 * 4)     // xr0
             + alignup(slots * 96 * 8)           // w0part i64
             + alignup(slots * 4 * 8)            // zpart i64
             + alignup((size_t)bcx * 96 * 4);    // row0v
    };
    int bc = BB;
    while (bc > 1 && need(bc) > ws_size) bc >>= 1;

    k_wprep<128><<<6, 256, 0, stream>>>(Wl1, wf1h, wf1l);
    k_wprep<96><<<5, 256, 0, stream>>>(Wl2, wf2h, wf2l);

    for (int cb = 0; cb < BB; cb += bc) {
        size_t rn = (size_t)bc * NN;
        size_t slots = (size_t)bc * 64;
        char* p = base;
        ushort_t*  Xbuf  = (ushort_t*)p;  p += alignup(rn * 128 * 2);
        ushort_t*  X2buf = (ushort_t*)p;  p += alignup(rn * 96 * 2);
        float*     xr0b  = (float*)p;     p += alignup((size_t)bc * 96 * 4);
        long long* w0pt  = (long long*)p; p += alignup(slots * 96 * 8);
        long long* zpt   = (long long*)p; p += alignup(slots * 4 * 8);
        float*     row0v = (float*)p;
        // pool partials overlay the (dead-after-conv1) Xbuf region
        long long* pspt = (long long*)Xbuf;
        long long* pwpt = pspt + slots * 96;

        const float* inC = in0 + (size_t)cb * NN * FIN;
        float* outC = (float*)d_out + (size_t)cb * 256;

        // stage 1
        k_fcnode<<<bc * NN / 64, 256, 0, stream>>>(inC, W_node, b_node, lnn_g, lnn_b, Xbuf);
        // xr0_1
        k_xr0<128><<<bc, 128, 0, stream>>>(Xbuf, Wr1, br1, xr0b);
        // conv1 (stores Xout; attention partials -> slots)
        k_conv<128, false><<<bc * NN / 128, 256, 0, stream>>>(
            Xbuf, wf1h, wf1l, bl1, att1, xr0b, bias1, lnc1_g, lnc1_b,
            w0pt, zpt, X2buf, nullptr, nullptr, nullptr);
        // node-0 finalize (conv1): combine slots, write X2 row 0
        k_row0<1><<<bc, 128, 0, stream>>>(w0pt, zpt, bias1, lnc1_g, lnc1_b,
                                          X2buf, nullptr);
        // xr0_2
        k_xr0<96><<<bc, 128, 0, stream>>>(X2buf, Wr2, br2, xr0b);
        // conv2 (attention + pool partials -> slots; Xbuf region now reused)
        k_conv<96, true><<<bc * NN / 128, 256, 0, stream>>>(
            X2buf, wf2h, wf2l, bl2, att2, xr0b, bias2, lnc2_g, lnc2_b,
            w0pt, zpt, nullptr, pspt, pwpt, tptr);
        // node-0 finalize (conv2): combine slots, write row0v
        k_row0<2><<<bc, 128, 0, stream>>>(w0pt, zpt, bias2, lnc2_g, lnc2_b,
                                          nullptr, row0v);
        // pool combine + output head
        k_out<<<bc, 128 + 128, 0, stream>>>(pspt, pwpt, row0v, tptr, W_out, b_out,
                                            lno_g, lno_b, outC);
    }
}

// Round 16
// 214.243 us; speedup vs baseline: 1.0157x; 1.0157x over previous
//
#include <hip/hip_runtime.h>
#include <hip/hip_bf16.h>
#include <math.h>

#define BB 128
#define NN 2048
#define FIN 17

#define SCALE_I 1048576.0f          // 2^20 fixed-point scale
#define INV_SCALE 9.5367431640625e-07f

typedef unsigned short ushort_t;
typedef __attribute__((ext_vector_type(4))) unsigned short u16x4;
typedef __attribute__((ext_vector_type(8))) short s16x8;
typedef __attribute__((ext_vector_type(4))) float f32x4;

__device__ __forceinline__ float b2f(unsigned short u) {
    unsigned int v = ((unsigned int)u) << 16;
    return __builtin_bit_cast(float, v);
}
__device__ __forceinline__ unsigned short f2b(float f) {
    __hip_bfloat16 h = __float2bfloat16(f);
    return __builtin_bit_cast(unsigned short, h);
}
// fast RNE f32->bf16 for finite values (no NaN path)
__device__ __forceinline__ unsigned short f2b_fast(float f) {
    unsigned int u = __builtin_bit_cast(unsigned int, f);
    u += 0x7FFFu + ((u >> 16) & 1u);
    return (unsigned short)(u >> 16);
}
// gelu via A&S 7.1.26 erf approx (|abs err| <= 1.5e-7)
__device__ __forceinline__ float gelu_f(float x) {
    float ax = fabsf(x) * 0.70710678118654752f;
    float t = 1.0f / (1.0f + 0.3275911f * ax);
    float poly = t * (0.254829592f +
                 t * (-0.284496736f +
                 t * (1.421413741f +
                 t * (-1.453152027f +
                 t * 1.061405429f))));
    float erfv = 1.0f - poly * __expf(-ax * ax);
    erfv = (x >= 0.f) ? erfv : -erfv;
    return 0.5f * x * (1.0f + erfv);
}
__device__ __forceinline__ float lrelu_f(float x) {
    return x >= 0.0f ? x : 0.2f * x;
}
// fixed-point quantize: EXACTLY the q20 used by the proven R13 arithmetic
__device__ __forceinline__ long long q20(float x) {
    return (long long)(x * SCALE_I);
}

// ---------------- Stage 1: x = LN(gelu(in @ W_node + b_node)) -> [Bc*N,128] bf16
// (R13 verbatim — numerics frozen)
__global__ __launch_bounds__(256) void k_fcnode(
    const float* __restrict__ X, const float* __restrict__ W,
    const float* __restrict__ bias, const float* __restrict__ g,
    const float* __restrict__ beta, ushort_t* __restrict__ out) {
    __shared__ float Ws[FIN * 128];
    __shared__ float xs[64 * FIN];
    __shared__ float bl[128], gl[128], bet[128];
    int tid = threadIdx.x;
    long long rbase = (long long)blockIdx.x * 64;
    for (int i = tid; i < FIN * 128; i += 256) Ws[i] = W[i];
    for (int i = tid; i < 64 * FIN; i += 256) xs[i] = X[rbase * FIN + i];
    if (tid < 128) {
        bl[tid] = bias[tid]; gl[tid] = g[tid]; bet[tid] = beta[tid];
    }
    __syncthreads();
    int lane32 = tid & 31, sub = tid >> 5;
    int c0 = 4 * lane32;
    f32x4 acc[8] = {};
#pragma unroll
    for (int k = 0; k < FIN; k++) {
        f32x4 w = *(const f32x4*)(Ws + k * 128 + c0);
#pragma unroll
        for (int r = 0; r < 8; r++) {
            float xv = xs[(sub + 8 * r) * FIN + k];
            acc[r][0] = fmaf(xv, w[0], acc[r][0]);
            acc[r][1] = fmaf(xv, w[1], acc[r][1]);
            acc[r][2] = fmaf(xv, w[2], acc[r][2]);
            acc[r][3] = fmaf(xv, w[3], acc[r][3]);
        }
    }
#pragma unroll
    for (int r = 0; r < 8; r++) {
        int lr = sub + 8 * r;
        float v[4], s = 0.f, sq = 0.f;
#pragma unroll
        for (int j = 0; j < 4; j++) {
            v[j] = gelu_f(acc[r][j] + bl[c0 + j]);
            s += v[j]; sq += v[j] * v[j];
        }
#pragma unroll
        for (int mk = 16; mk >= 1; mk >>= 1) {
            s += __shfl_xor(s, mk, 32); sq += __shfl_xor(sq, mk, 32);
        }
        float mean = s * (1.f / 128.f);
        float var = sq * (1.f / 128.f) - mean * mean;
        float rstd = rsqrtf(var + 1e-5f);
        u16x4 o4;
#pragma unroll
        for (int j = 0; j < 4; j++)
            o4[j] = f2b_fast((v[j] - mean) * rstd * gl[c0 + j] + bet[c0 + j]);
        *(u16x4*)(out + (rbase + lr) * 128 + c0) = o4;
    }
}

// ---------------- W fragment prep: f32 [K,96] -> bf16 hi/lo in MFMA B-lane layout
template <int K>
__global__ __launch_bounds__(256) void k_wprep(
    const float* __restrict__ W, ushort_t* __restrict__ hi, ushort_t* __restrict__ lo) {
    constexpr int S = K / 32;
    int gid = blockIdx.x * 256 + threadIdx.x;
    if (gid >= 6 * S * 64) return;
    int lane = gid & 63, f = gid >> 6;
    int t = f / S, s = f - t * S;
    int n = 16 * t + (lane & 15);
    int kbase = 32 * s + 8 * (lane >> 4);
#pragma unroll
    for (int j = 0; j < 8; j++) {
        float w = W[(kbase + j) * 96 + n];
        ushort_t h = f2b(w);
        float rem = w - b2f(h);
        hi[gid * 8 + j] = h;
        lo[gid * 8 + j] = f2b(rem);
    }
}

// ---------------- xr0[b] = X[b,0,:] @ Wr + br  -> [Bc,96] f32 (conv1 only)
template <int K>
__global__ __launch_bounds__(128) void k_xr0(
    const ushort_t* __restrict__ X, const float* __restrict__ Wr,
    const float* __restrict__ br, float* __restrict__ xr0) {
    int b = blockIdx.x, c = threadIdx.x;
    __shared__ float xs[K];
    if (threadIdx.x < K) xs[threadIdx.x] = b2f(X[(long long)b * NN * K + threadIdx.x]);
    __syncthreads();
    if (c >= 96) return;
    float acc = br[c];
    for (int k = 0; k < K; k++) acc = fmaf(xs[k], Wr[k * 96 + c], acc);
    xr0[b * 96 + c] = acc;
}

// ---------------- MFMA conv with fused attention (+pool) partials.
// Block = 512 thr = 8 waves; wave: 32 rows x 96 cols (256 rows/block).
// Per-wave arithmetic IDENTICAL to R13 (bit-exact); only block grouping
// changed so W staging+barriers amortize over 2x rows. W hi+lo in LDS.
// DETERMINISTIC BY CONSTRUCTION: plain-stores of q20 int64 partials to fixed
// slots (slot = row0>>5). No atomics, no RMW.
template <int K, bool POOLF>
__global__ __launch_bounds__(512) void k_conv(
    const ushort_t* __restrict__ X,     // [Bc*N,K] bf16
    const ushort_t* __restrict__ Whi, const ushort_t* __restrict__ Wlo,
    const float* __restrict__ bl, const float* __restrict__ att,
    const float* __restrict__ xr0,      // [Bc,96]
    const float* __restrict__ bias, const float* __restrict__ lng,
    const float* __restrict__ lnb,
    long long* __restrict__ w0part,     // [Bc*64, 96] q20 sum e*xl per slot
    long long* __restrict__ zpart,      // [Bc*64, 4]  q20 sum e per head
    ushort_t* __restrict__ Xout,        // layer1: [Bc*N,96] bf16
    long long* __restrict__ pspart,     // layer2: [Bc*64, 96] q20 sum pe
    long long* __restrict__ pwpart,     // layer2: [Bc*64, 96] q20 sum pe*v
    const float* __restrict__ tptr)
{
    constexpr int S = K / 32;
    constexpr int NFRAG = 6 * S * 64;
    __shared__ s16x8 lWh[NFRAG];
    __shared__ s16x8 lWl[NFRAG];
    int tid = threadIdx.x;
    {
        const s16x8* gh = (const s16x8*)Whi;
        const s16x8* gl8 = (const s16x8*)Wlo;
        for (int i = tid; i < NFRAG; i += 512) {
            lWh[i] = gh[i];
            lWl[i] = gl8[i];
        }
    }
    __syncthreads();

    int wave = tid >> 6, lane = tid & 63;
    int hi4 = lane >> 4, cl = lane & 15;
    int row0 = blockIdx.x * 256 + wave * 32;
    int b = row0 >> 11;     // chunk-local batch (NN=2048)
    int slot = row0 >> 5;   // batch b owns slots [b*64, b*64+64)

    f32x4 acc[2][6] = {};
#pragma unroll
    for (int s = 0; s < S; s++) {
        s16x8 a0 = *(const s16x8*)(X + (size_t)(row0 + cl) * K + s * 32 + hi4 * 8);
        s16x8 a1 = *(const s16x8*)(X + (size_t)(row0 + 16 + cl) * K + s * 32 + hi4 * 8);
#pragma unroll
        for (int t = 0; t < 6; t++) {
            s16x8 bh = lWh[(t * S + s) * 64 + lane];
            s16x8 bo = lWl[(t * S + s) * 64 + lane];
            acc[0][t] = __builtin_amdgcn_mfma_f32_16x16x32_bf16(a0, bh, acc[0][t], 0, 0, 0);
            acc[0][t] = __builtin_amdgcn_mfma_f32_16x16x32_bf16(a0, bo, acc[0][t], 0, 0, 0);
            acc[1][t] = __builtin_amdgcn_mfma_f32_16x16x32_bf16(a1, bh, acc[1][t], 0, 0, 0);
            acc[1][t] = __builtin_amdgcn_mfma_f32_16x16x32_bf16(a1, bo, acc[1][t], 0, 0, 0);
        }
    }

    float blc[6], xrc[6], attc[6], bic[6], gc[6], bcc[6];
#pragma unroll
    for (int t = 0; t < 6; t++) {
        int c = 16 * t + cl;
        blc[t] = bl[c]; xrc[t] = xr0[b * 96 + c]; attc[t] = att[c];
        bic[t] = bias[c]; gc[t] = lng[c]; bcc[t] = lnb[c];
    }
    float tv = POOLF ? tptr[0] : 0.f;

    float w0p[6] = {0.f, 0.f, 0.f, 0.f, 0.f, 0.f};
    float zp[3] = {0.f, 0.f, 0.f};
    float psp[6] = {0.f, 0.f, 0.f, 0.f, 0.f, 0.f};
    float pwp[6] = {0.f, 0.f, 0.f, 0.f, 0.f, 0.f};

#pragma unroll
    for (int q = 0; q < 2; q++) {
#pragma unroll
        for (int i = 0; i < 4; i++) {
            int row = row0 + q * 16 + hi4 * 4 + i;
            float xl[6];
#pragma unroll
            for (int t = 0; t < 6; t++) xl[t] = acc[q][t][i] + blc[t];
            // score partials per head (pre-reduction)
            float pv[6];
#pragma unroll
            for (int t = 0; t < 6; t++) pv[t] = attc[t] * lrelu_f(xl[t] + xrc[t]);
            float p0 = pv[0] + pv[1], p1 = pv[2] + pv[3], p2 = pv[4] + pv[5];
            // output-path gelu partials (independent of scores)
            float o[6], s = 0.f, sq = 0.f;
#pragma unroll
            for (int t = 0; t < 6; t++) {
                o[t] = gelu_f(xl[t] + bic[t]);
                s += o[t]; sq += o[t] * o[t];
            }
            // single combined 4-step tree over the 16-lane cl group
#pragma unroll
            for (int mk = 1; mk <= 8; mk <<= 1) {
                p0 += __shfl_xor(p0, mk, 64);
                p1 += __shfl_xor(p1, mk, 64);
                p2 += __shfl_xor(p2, mk, 64);
                s  += __shfl_xor(s,  mk, 64);
                sq += __shfl_xor(sq, mk, 64);
            }
            float e0 = __expf(fminf(p0, 24.f));
            float e1 = __expf(fminf(p1, 24.f));
            float e2 = __expf(fminf(p2, 24.f));
            w0p[0] = fmaf(e0, xl[0], w0p[0]); w0p[1] = fmaf(e0, xl[1], w0p[1]);
            w0p[2] = fmaf(e1, xl[2], w0p[2]); w0p[3] = fmaf(e1, xl[3], w0p[3]);
            w0p[4] = fmaf(e2, xl[4], w0p[4]); w0p[5] = fmaf(e2, xl[5], w0p[5]);
            zp[0] += e0; zp[1] += e1; zp[2] += e2;
            float mean = s * (1.f / 96.f);
            float var = sq * (1.f / 96.f) - mean * mean;
            float rstd = rsqrtf(var + 1e-5f);
            if ((row & (NN - 1)) != 0) {
                if (!POOLF) {
#pragma unroll
                    for (int t = 0; t < 6; t++)
                        Xout[(size_t)row * 96 + 16 * t + cl] =
                            f2b_fast((o[t] - mean) * rstd * gc[t] + bcc[t]);
                } else {
#pragma unroll
                    for (int t = 0; t < 6; t++) {
                        float v = (o[t] - mean) * rstd * gc[t] + bcc[t];
                        float pe = __expf(fminf(tv * v, 24.f));
                        psp[t] += pe;
                        pwp[t] = fmaf(pe, v, pwp[t]);
                    }
                }
            }
        }
    }

    // reduce across the 4 hi4 groups (lanes cl, cl+16, cl+32, cl+48)
#pragma unroll
    for (int t = 0; t < 6; t++) {
        w0p[t] += __shfl_xor(w0p[t], 16, 64);
        w0p[t] += __shfl_xor(w0p[t], 32, 64);
    }
#pragma unroll
    for (int h = 0; h < 3; h++) {
        zp[h] += __shfl_xor(zp[h], 16, 64);
        zp[h] += __shfl_xor(zp[h], 32, 64);
    }
    if (POOLF) {
#pragma unroll
        for (int t = 0; t < 6; t++) {
            psp[t] += __shfl_xor(psp[t], 16, 64);
            psp[t] += __shfl_xor(psp[t], 32, 64);
            pwp[t] += __shfl_xor(pwp[t], 16, 64);
            pwp[t] += __shfl_xor(pwp[t], 32, 64);
        }
    }
    // plain stores of q20 integers to this wave's fixed slot
    if (lane < 16) {
#pragma unroll
        for (int t = 0; t < 6; t++)
            w0part[(size_t)slot * 96 + 16 * t + lane] = q20(w0p[t]);
        if (POOLF) {
#pragma unroll
            for (int t = 0; t < 6; t++) {
                pspart[(size_t)slot * 96 + 16 * t + lane] = q20(psp[t]);
                pwpart[(size_t)slot * 96 + 16 * t + lane] = q20(pwp[t]);
            }
        }
    }
    if (lane == 0) {
        zpart[slot * 4 + 0] = q20(zp[0]);
        zpart[slot * 4 + 1] = q20(zp[1]);
        zpart[slot * 4 + 2] = q20(zp[2]);
        zpart[slot * 4 + 3] = 0ll;
    }
}

// ---------------- combine slots (exact integer sums) + finalize node-0 row.
// LAYER 1: write X2 row 0 (bf16) AND fused xr0_2 (bit-exact vs k_xr0<96>:
//          dot uses b2f(f2b(ln)) with k-ascending fmaf, identical order).
// LAYER 2: write row-0 LN value to row0v.
template <int LAYER>
__global__ __launch_bounds__(128) void k_row0(
    const long long* __restrict__ w0part, const long long* __restrict__ zpart,
    const float* __restrict__ bias, const float* __restrict__ g,
    const float* __restrict__ beta, ushort_t* __restrict__ X2,
    float* __restrict__ row0v,
    const float* __restrict__ Wr2, const float* __restrict__ br2,
    float* __restrict__ xr0out) {
    int b = blockIdx.x, t = threadIdx.x;
    __shared__ float vv[96];
    __shared__ float lnS[96];
    __shared__ float red2[2];
    __shared__ float zs[3];
    if (t < 3) {
        long long z = 0;
        for (int s = 0; s < 64; s++) z += zpart[(b * 64 + s) * 4 + t];
        zs[t] = (float)z;
    }
    long long wsum = 0;
    if (t < 96) {
        for (int s = 0; s < 64; s++)
            wsum += w0part[(size_t)(b * 64 + s) * 96 + t];
    }
    __syncthreads();
    float val = 0.f;
    if (t < 96) {
        float wf = (float)wsum;
        float zf = zs[t >> 5];
        val = gelu_f(wf / zf + bias[t]);   // fixed-point scale cancels
        vv[t] = val;
    }
    __syncthreads();
    if (t < 32) {
        float a = vv[t], b2 = vv[t + 32], c = vv[t + 64];
        float s = a + b2 + c, sq = a * a + b2 * b2 + c * c;
#pragma unroll
        for (int mk = 16; mk >= 1; mk >>= 1) { s += __shfl_xor(s, mk, 32); sq += __shfl_xor(sq, mk, 32); }
        if (t == 0) { red2[0] = s; red2[1] = sq; }
    }
    __syncthreads();
    float mean = red2[0] * (1.f / 96.f);
    float var = red2[1] * (1.f / 96.f) - mean * mean;
    float rstd = rsqrtf(var + 1e-5f);
    if (t < 96) {
        float ln = (val - mean) * rstd * g[t] + beta[t];
        if (LAYER == 1) {
            ushort_t lb = f2b(ln);
            X2[(long long)b * NN * 96 + t] = lb;
            lnS[t] = b2f(lb);          // exactly what k_xr0<96> would read
        } else {
            row0v[b * 96 + t] = ln;
        }
    }
    if (LAYER == 1) {
        __syncthreads();
        if (t < 96) {
            float a = br2[t];
            for (int k = 0; k < 96; k++)
                a = fmaf(lnS[k], Wr2[k * 96 + t], a);   // same order as k_xr0
            xr0out[b * 96 + t] = a;
        }
    }
}

// ---------------- final: pool combine (exact integer sums + row-0 term)
// then out = LN(gelu(pooled @ W_out + b_out)) -> [Bc,256]
__global__ __launch_bounds__(256) void k_out(
    const long long* __restrict__ pspart, const long long* __restrict__ pwpart,
    const float* __restrict__ row0v, const float* __restrict__ tptr,
    const float* __restrict__ W, const float* __restrict__ bias,
    const float* __restrict__ g, const float* __restrict__ beta,
    float* __restrict__ out) {
    int b = blockIdx.x, c = threadIdx.x;
    __shared__ float ps[96];
    __shared__ float rs[4], rq[4];
    if (c < 96) {
        long long Si = 0, Wi = 0;
        for (int s = 0; s < 64; s++) {
            Si += pspart[(size_t)(b * 64 + s) * 96 + c];
            Wi += pwpart[(size_t)(b * 64 + s) * 96 + c];
        }
        float ln0 = row0v[b * 96 + c];
        float pe0 = __expf(fminf(tptr[0] * ln0, 24.f));
        float S = (float)Si * INV_SCALE + pe0;
        float Wp = (float)Wi * INV_SCALE + pe0 * ln0;
        ps[c] = Wp / S;
    }
    __syncthreads();
    float acc = bias[c];
    for (int k = 0; k < 96; k++) acc = fmaf(ps[k], W[k * 256 + c], acc);
    float v = gelu_f(acc);
    float s = v, sq = v * v;
#pragma unroll
    for (int mk = 32; mk >= 1; mk >>= 1) { s += __shfl_xor(s, mk, 64); sq += __shfl_xor(sq, mk, 64); }
    if ((c & 63) == 0) { rs[c >> 6] = s; rq[c >> 6] = sq; }
    __syncthreads();
    s = rs[0] + rs[1] + rs[2] + rs[3];
    sq = rq[0] + rq[1] + rq[2] + rq[3];
    float mean = s * (1.f / 256.f);
    float var = sq * (1.f / 256.f) - mean * mean;
    float rstd = rsqrtf(var + 1e-5f);
    out[b * 256 + c] = (v - mean) * rstd * g[c] + beta[c];
}

extern "C" void kernel_launch(void* const* d_in, const int* in_sizes, int n_in,
                              void* d_out, int out_size, void* d_ws, size_t ws_size,
                              hipStream_t stream) {
    const float* in0    = (const float*)d_in[0];
    const float* W_node = (const float*)d_in[1];
    const float* b_node = (const float*)d_in[2];
    const float* lnn_g  = (const float*)d_in[3];
    const float* lnn_b  = (const float*)d_in[4];
    const float* Wl1 = (const float*)d_in[5];
    const float* bl1 = (const float*)d_in[6];
    const float* Wr1 = (const float*)d_in[7];
    const float* br1 = (const float*)d_in[8];
    const float* att1 = (const float*)d_in[9];
    const float* bias1 = (const float*)d_in[10];
    const float* lnc1_g = (const float*)d_in[11];
    const float* lnc1_b = (const float*)d_in[12];
    const float* Wl2 = (const float*)d_in[13];
    const float* bl2 = (const float*)d_in[14];
    const float* Wr2 = (const float*)d_in[15];
    const float* br2 = (const float*)d_in[16];
    const float* att2 = (const float*)d_in[17];
    const float* bias2 = (const float*)d_in[18];
    const float* lnc2_g = (const float*)d_in[19];
    const float* lnc2_b = (const float*)d_in[20];
    const float* tptr = (const float*)d_in[21];
    const float* W_out = (const float*)d_in[22];
    const float* b_out = (const float*)d_in[23];
    const float* lno_g = (const float*)d_in[24];
    const float* lno_b = (const float*)d_in[25];

    auto alignup = [](size_t x) { return (x + 255) & ~(size_t)255; };

    // fixed region: MFMA B-fragments (hi/lo) for both conv layers
    const size_t wf1 = (size_t)6 * 4 * 64 * 8;  // K=128
    const size_t wf2 = (size_t)6 * 3 * 64 * 8;  // K=96
    char* base = (char*)d_ws;
    ushort_t* wf1h = (ushort_t*)base;             base += alignup(wf1 * 2);
    ushort_t* wf1l = (ushort_t*)base;             base += alignup(wf1 * 2);
    ushort_t* wf2h = (ushort_t*)base;             base += alignup(wf2 * 2);
    ushort_t* wf2l = (ushort_t*)base;             base += alignup(wf2 * 2);
    size_t fixed = (size_t)(base - (char*)d_ws);

    // per-chunk: X bf16, X2 bf16, xr0, w0part(i64), zpart(i64), row0v.
    // pool slot arrays (pspart/pwpart, i64) alias the Xbuf region (dead
    // after conv1; 2*slots*96*8 = 12.6 MB << Xbuf 67 MB at bc=128).
    auto need = [&](int bcx) -> size_t {
        size_t rn = (size_t)bcx * NN;
        size_t slots = (size_t)bcx * 64;
        return fixed
             + alignup(rn * 128 * 2)             // X bf16 (holds ps/pw i64 later)
             + alignup(rn * 96 * 2)              // X2 bf16
             + alignup((size_t)bcx * 96 * 4)     // xr0
             + alignup(slots * 96 * 8)           // w0part i64
             + alignup(slots * 4 * 8)            // zpart i64
             + alignup((size_t)bcx * 96 * 4);    // row0v
    };
    int bc = BB;
    while (bc > 1 && need(bc) > ws_size) bc >>= 1;

    k_wprep<128><<<6, 256, 0, stream>>>(Wl1, wf1h, wf1l);
    k_wprep<96><<<5, 256, 0, stream>>>(Wl2, wf2h, wf2l);

    for (int cb = 0; cb < BB; cb += bc) {
        size_t rn = (size_t)bc * NN;
        size_t slots = (size_t)bc * 64;
        char* p = base;
        ushort_t*  Xbuf  = (ushort_t*)p;  p += alignup(rn * 128 * 2);
        ushort_t*  X2buf = (ushort_t*)p;  p += alignup(rn * 96 * 2);
        float*     xr0b  = (float*)p;     p += alignup((size_t)bc * 96 * 4);
        long long* w0pt  = (long long*)p; p += alignup(slots * 96 * 8);
        long long* zpt   = (long long*)p; p += alignup(slots * 4 * 8);
        float*     row0v = (float*)p;
        // pool partials overlay the (dead-after-conv1) Xbuf region
        long long* pspt = (long long*)Xbuf;
        long long* pwpt = pspt + slots * 96;

        const float* inC = in0 + (size_t)cb * NN * FIN;
        float* outC = (float*)d_out + (size_t)cb * 256;

        // stage 1
        k_fcnode<<<bc * NN / 64, 256, 0, stream>>>(inC, W_node, b_node, lnn_g, lnn_b, Xbuf);
        // xr0_1
        k_xr0<128><<<bc, 128, 0, stream>>>(Xbuf, Wr1, br1, xr0b);
        // conv1 (stores Xout; attention partials -> slots), 8-wave blocks
        k_conv<128, false><<<bc * NN / 256, 512, 0, stream>>>(
            Xbuf, wf1h, wf1l, bl1, att1, xr0b, bias1, lnc1_g, lnc1_b,
            w0pt, zpt, X2buf, nullptr, nullptr, nullptr);
        // node-0 finalize (conv1): combine slots, write X2 row 0 + fused xr0_2
        k_row0<1><<<bc, 128, 0, stream>>>(w0pt, zpt, bias1, lnc1_g, lnc1_b,
                                          X2buf, nullptr, Wr2, br2, xr0b);
        // conv2 (attention + pool partials -> slots; Xbuf region now reused)
        k_conv<96, true><<<bc * NN / 256, 512, 0, stream>>>(
            X2buf, wf2h, wf2l, bl2, att2, xr0b, bias2, lnc2_g, lnc2_b,
            w0pt, zpt, nullptr, pspt, pwpt, tptr);
        // node-0 finalize (conv2): combine slots, write row0v
        k_row0<2><<<bc, 128, 0, stream>>>(w0pt, zpt, bias2, lnc2_g, lnc2_b,
                                          nullptr, row0v, nullptr, nullptr, nullptr);
        // pool combine + output head
        k_out<<<bc, 256, 0, stream>>>(pspt, pwpt, row0v, tptr, W_out, b_out,
                                      lno_g, lno_b, outC);
    }
}

// Round 17
// 211.923 us; speedup vs baseline: 1.0268x; 1.0109x over previous
//
#include <hip/hip_runtime.h>
#include <hip/hip_bf16.h>
#include <math.h>

#define BB 128
#define NN 2048
#define FIN 17

#define SCALE_I 1048576.0f          // 2^20 fixed-point scale
#define INV_SCALE 9.5367431640625e-07f

typedef unsigned short ushort_t;
typedef __attribute__((ext_vector_type(4))) unsigned short u16x4;
typedef __attribute__((ext_vector_type(8))) short s16x8;
typedef __attribute__((ext_vector_type(4))) float f32x4;

__device__ __forceinline__ float b2f(unsigned short u) {
    unsigned int v = ((unsigned int)u) << 16;
    return __builtin_bit_cast(float, v);
}
__device__ __forceinline__ unsigned short f2b(float f) {
    __hip_bfloat16 h = __float2bfloat16(f);
    return __builtin_bit_cast(unsigned short, h);
}
// fast RNE f32->bf16 for finite values (no NaN path)
__device__ __forceinline__ unsigned short f2b_fast(float f) {
    unsigned int u = __builtin_bit_cast(unsigned int, f);
    u += 0x7FFFu + ((u >> 16) & 1u);
    return (unsigned short)(u >> 16);
}
// gelu via A&S 7.1.26 erf approx (|abs err| <= 1.5e-7)
__device__ __forceinline__ float gelu_f(float x) {
    float ax = fabsf(x) * 0.70710678118654752f;
    float t = 1.0f / (1.0f + 0.3275911f * ax);
    float poly = t * (0.254829592f +
                 t * (-0.284496736f +
                 t * (1.421413741f +
                 t * (-1.453152027f +
                 t * 1.061405429f))));
    float erfv = 1.0f - poly * __expf(-ax * ax);
    erfv = (x >= 0.f) ? erfv : -erfv;
    return 0.5f * x * (1.0f + erfv);
}
__device__ __forceinline__ float lrelu_f(float x) {
    return x >= 0.0f ? x : 0.2f * x;
}
// fixed-point quantize: EXACTLY the q20 used by the proven R13 arithmetic
__device__ __forceinline__ long long q20(float x) {
    return (long long)(x * SCALE_I);
}

// ---------------- Stage 1: x = LN(gelu(in @ W_node + b_node)) -> [Bc*N,128] bf16
// (R13 verbatim — numerics frozen)
__global__ __launch_bounds__(256) void k_fcnode(
    const float* __restrict__ X, const float* __restrict__ W,
    const float* __restrict__ bias, const float* __restrict__ g,
    const float* __restrict__ beta, ushort_t* __restrict__ out) {
    __shared__ float Ws[FIN * 128];
    __shared__ float xs[64 * FIN];
    __shared__ float bl[128], gl[128], bet[128];
    int tid = threadIdx.x;
    long long rbase = (long long)blockIdx.x * 64;
    for (int i = tid; i < FIN * 128; i += 256) Ws[i] = W[i];
    for (int i = tid; i < 64 * FIN; i += 256) xs[i] = X[rbase * FIN + i];
    if (tid < 128) {
        bl[tid] = bias[tid]; gl[tid] = g[tid]; bet[tid] = beta[tid];
    }
    __syncthreads();
    int lane32 = tid & 31, sub = tid >> 5;
    int c0 = 4 * lane32;
    f32x4 acc[8] = {};
#pragma unroll
    for (int k = 0; k < FIN; k++) {
        f32x4 w = *(const f32x4*)(Ws + k * 128 + c0);
#pragma unroll
        for (int r = 0; r < 8; r++) {
            float xv = xs[(sub + 8 * r) * FIN + k];
            acc[r][0] = fmaf(xv, w[0], acc[r][0]);
            acc[r][1] = fmaf(xv, w[1], acc[r][1]);
            acc[r][2] = fmaf(xv, w[2], acc[r][2]);
            acc[r][3] = fmaf(xv, w[3], acc[r][3]);
        }
    }
#pragma unroll
    for (int r = 0; r < 8; r++) {
        int lr = sub + 8 * r;
        float v[4], s = 0.f, sq = 0.f;
#pragma unroll
        for (int j = 0; j < 4; j++) {
            v[j] = gelu_f(acc[r][j] + bl[c0 + j]);
            s += v[j]; sq += v[j] * v[j];
        }
#pragma unroll
        for (int mk = 16; mk >= 1; mk >>= 1) {
            s += __shfl_xor(s, mk, 32); sq += __shfl_xor(sq, mk, 32);
        }
        float mean = s * (1.f / 128.f);
        float var = sq * (1.f / 128.f) - mean * mean;
        float rstd = rsqrtf(var + 1e-5f);
        u16x4 o4;
#pragma unroll
        for (int j = 0; j < 4; j++)
            o4[j] = f2b_fast((v[j] - mean) * rstd * gl[c0 + j] + bet[c0 + j]);
        *(u16x4*)(out + (rbase + lr) * 128 + c0) = o4;
    }
}

// ---------------- W fragment prep: f32 [K,96] -> bf16 hi/lo in MFMA B-lane layout
template <int K>
__global__ __launch_bounds__(256) void k_wprep(
    const float* __restrict__ W, ushort_t* __restrict__ hi, ushort_t* __restrict__ lo) {
    constexpr int S = K / 32;
    int gid = blockIdx.x * 256 + threadIdx.x;
    if (gid >= 6 * S * 64) return;
    int lane = gid & 63, f = gid >> 6;
    int t = f / S, s = f - t * S;
    int n = 16 * t + (lane & 15);
    int kbase = 32 * s + 8 * (lane >> 4);
#pragma unroll
    for (int j = 0; j < 8; j++) {
        float w = W[(kbase + j) * 96 + n];
        ushort_t h = f2b(w);
        float rem = w - b2f(h);
        hi[gid * 8 + j] = h;
        lo[gid * 8 + j] = f2b(rem);
    }
}

// ---------------- xr0[b] = X[b,0,:] @ Wr + br  -> [Bc,96] f32 (conv1 only)
template <int K>
__global__ __launch_bounds__(128) void k_xr0(
    const ushort_t* __restrict__ X, const float* __restrict__ Wr,
    const float* __restrict__ br, float* __restrict__ xr0) {
    int b = blockIdx.x, c = threadIdx.x;
    __shared__ float xs[K];
    if (threadIdx.x < K) xs[threadIdx.x] = b2f(X[(long long)b * NN * K + threadIdx.x]);
    __syncthreads();
    if (c >= 96) return;
    float acc = br[c];
    for (int k = 0; k < K; k++) acc = fmaf(xs[k], Wr[k * 96 + c], acc);
    xr0[b * 96 + c] = acc;
}

// ---------------- MFMA conv with fused attention (+pool) partials.
// R13 verbatim: block = 256 thr = 4 waves; wave: 32 rows x 96 cols
// (128 rows/block). W hi+lo staged in LDS.
// DETERMINISTIC BY CONSTRUCTION: plain-stores of q20 int64 partials to fixed
// slots (slot = row0>>5). No atomics, no RMW.
template <int K, bool POOLF>
__global__ __launch_bounds__(256) void k_conv(
    const ushort_t* __restrict__ X,     // [Bc*N,K] bf16
    const ushort_t* __restrict__ Whi, const ushort_t* __restrict__ Wlo,
    const float* __restrict__ bl, const float* __restrict__ att,
    const float* __restrict__ xr0,      // [Bc,96]
    const float* __restrict__ bias, const float* __restrict__ lng,
    const float* __restrict__ lnb,
    long long* __restrict__ w0part,     // [Bc*64, 96] q20 sum e*xl per slot
    long long* __restrict__ zpart,      // [Bc*64, 4]  q20 sum e per head
    ushort_t* __restrict__ Xout,        // layer1: [Bc*N,96] bf16
    long long* __restrict__ pspart,     // layer2: [Bc*64, 96] q20 sum pe
    long long* __restrict__ pwpart,     // layer2: [Bc*64, 96] q20 sum pe*v
    const float* __restrict__ tptr)
{
    constexpr int S = K / 32;
    constexpr int NFRAG = 6 * S * 64;
    __shared__ s16x8 lWh[NFRAG];
    __shared__ s16x8 lWl[NFRAG];
    int tid = threadIdx.x;
    {
        const s16x8* gh = (const s16x8*)Whi;
        const s16x8* gl8 = (const s16x8*)Wlo;
        for (int i = tid; i < NFRAG; i += 256) {
            lWh[i] = gh[i];
            lWl[i] = gl8[i];
        }
    }
    __syncthreads();

    int wave = tid >> 6, lane = tid & 63;
    int hi4 = lane >> 4, cl = lane & 15;
    int row0 = blockIdx.x * 128 + wave * 32;
    int b = row0 >> 11;     // chunk-local batch (NN=2048)
    int slot = row0 >> 5;   // batch b owns slots [b*64, b*64+64)

    f32x4 acc[2][6] = {};
#pragma unroll
    for (int s = 0; s < S; s++) {
        s16x8 a0 = *(const s16x8*)(X + (size_t)(row0 + cl) * K + s * 32 + hi4 * 8);
        s16x8 a1 = *(const s16x8*)(X + (size_t)(row0 + 16 + cl) * K + s * 32 + hi4 * 8);
#pragma unroll
        for (int t = 0; t < 6; t++) {
            s16x8 bh = lWh[(t * S + s) * 64 + lane];
            s16x8 bo = lWl[(t * S + s) * 64 + lane];
            acc[0][t] = __builtin_amdgcn_mfma_f32_16x16x32_bf16(a0, bh, acc[0][t], 0, 0, 0);
            acc[0][t] = __builtin_amdgcn_mfma_f32_16x16x32_bf16(a0, bo, acc[0][t], 0, 0, 0);
            acc[1][t] = __builtin_amdgcn_mfma_f32_16x16x32_bf16(a1, bh, acc[1][t], 0, 0, 0);
            acc[1][t] = __builtin_amdgcn_mfma_f32_16x16x32_bf16(a1, bo, acc[1][t], 0, 0, 0);
        }
    }

    float blc[6], xrc[6], attc[6], bic[6], gc[6], bcc[6];
#pragma unroll
    for (int t = 0; t < 6; t++) {
        int c = 16 * t + cl;
        blc[t] = bl[c]; xrc[t] = xr0[b * 96 + c]; attc[t] = att[c];
        bic[t] = bias[c]; gc[t] = lng[c]; bcc[t] = lnb[c];
    }
    float tv = POOLF ? tptr[0] : 0.f;

    float w0p[6] = {0.f, 0.f, 0.f, 0.f, 0.f, 0.f};
    float zp[3] = {0.f, 0.f, 0.f};
    float psp[6] = {0.f, 0.f, 0.f, 0.f, 0.f, 0.f};
    float pwp[6] = {0.f, 0.f, 0.f, 0.f, 0.f, 0.f};

#pragma unroll
    for (int q = 0; q < 2; q++) {
#pragma unroll
        for (int i = 0; i < 4; i++) {
            int row = row0 + q * 16 + hi4 * 4 + i;
            float xl[6];
#pragma unroll
            for (int t = 0; t < 6; t++) xl[t] = acc[q][t][i] + blc[t];
            // score partials per head (pre-reduction)
            float pv[6];
#pragma unroll
            for (int t = 0; t < 6; t++) pv[t] = attc[t] * lrelu_f(xl[t] + xrc[t]);
            float p0 = pv[0] + pv[1], p1 = pv[2] + pv[3], p2 = pv[4] + pv[5];
            // output-path gelu partials (independent of scores)
            float o[6], s = 0.f, sq = 0.f;
#pragma unroll
            for (int t = 0; t < 6; t++) {
                o[t] = gelu_f(xl[t] + bic[t]);
                s += o[t]; sq += o[t] * o[t];
            }
            // single combined 4-step tree over the 16-lane cl group
#pragma unroll
            for (int mk = 1; mk <= 8; mk <<= 1) {
                p0 += __shfl_xor(p0, mk, 64);
                p1 += __shfl_xor(p1, mk, 64);
                p2 += __shfl_xor(p2, mk, 64);
                s  += __shfl_xor(s,  mk, 64);
                sq += __shfl_xor(sq, mk, 64);
            }
            float e0 = __expf(fminf(p0, 24.f));
            float e1 = __expf(fminf(p1, 24.f));
            float e2 = __expf(fminf(p2, 24.f));
            w0p[0] = fmaf(e0, xl[0], w0p[0]); w0p[1] = fmaf(e0, xl[1], w0p[1]);
            w0p[2] = fmaf(e1, xl[2], w0p[2]); w0p[3] = fmaf(e1, xl[3], w0p[3]);
            w0p[4] = fmaf(e2, xl[4], w0p[4]); w0p[5] = fmaf(e2, xl[5], w0p[5]);
            zp[0] += e0; zp[1] += e1; zp[2] += e2;
            float mean = s * (1.f / 96.f);
            float var = sq * (1.f / 96.f) - mean * mean;
            float rstd = rsqrtf(var + 1e-5f);
            if ((row & (NN - 1)) != 0) {
                if (!POOLF) {
#pragma unroll
                    for (int t = 0; t < 6; t++)
                        Xout[(size_t)row * 96 + 16 * t + cl] =
                            f2b_fast((o[t] - mean) * rstd * gc[t] + bcc[t]);
                } else {
#pragma unroll
                    for (int t = 0; t < 6; t++) {
                        float v = (o[t] - mean) * rstd * gc[t] + bcc[t];
                        float pe = __expf(fminf(tv * v, 24.f));
                        psp[t] += pe;
                        pwp[t] = fmaf(pe, v, pwp[t]);
                    }
                }
            }
        }
    }

    // reduce across the 4 hi4 groups (lanes cl, cl+16, cl+32, cl+48)
#pragma unroll
    for (int t = 0; t < 6; t++) {
        w0p[t] += __shfl_xor(w0p[t], 16, 64);
        w0p[t] += __shfl_xor(w0p[t], 32, 64);
    }
#pragma unroll
    for (int h = 0; h < 3; h++) {
        zp[h] += __shfl_xor(zp[h], 16, 64);
        zp[h] += __shfl_xor(zp[h], 32, 64);
    }
    if (POOLF) {
#pragma unroll
        for (int t = 0; t < 6; t++) {
            psp[t] += __shfl_xor(psp[t], 16, 64);
            psp[t] += __shfl_xor(psp[t], 32, 64);
            pwp[t] += __shfl_xor(pwp[t], 16, 64);
            pwp[t] += __shfl_xor(pwp[t], 32, 64);
        }
    }
    // plain stores of q20 integers to this wave's fixed slot
    if (lane < 16) {
#pragma unroll
        for (int t = 0; t < 6; t++)
            w0part[(size_t)slot * 96 + 16 * t + lane] = q20(w0p[t]);
        if (POOLF) {
#pragma unroll
            for (int t = 0; t < 6; t++) {
                pspart[(size_t)slot * 96 + 16 * t + lane] = q20(psp[t]);
                pwpart[(size_t)slot * 96 + 16 * t + lane] = q20(pwp[t]);
            }
        }
    }
    if (lane == 0) {
        zpart[slot * 4 + 0] = q20(zp[0]);
        zpart[slot * 4 + 1] = q20(zp[1]);
        zpart[slot * 4 + 2] = q20(zp[2]);
        zpart[slot * 4 + 3] = 0ll;
    }
}

// ---------------- combine slots (exact integer sums) + finalize node-0 row.
// LAYER 1: write X2 row 0 (bf16) AND fused xr0_2 (bit-exact vs k_xr0<96>:
//          dot uses b2f(f2b(ln)) with k-ascending fmaf, identical order).
// LAYER 2: write row-0 LN value to row0v.
template <int LAYER>
__global__ __launch_bounds__(128) void k_row0(
    const long long* __restrict__ w0part, const long long* __restrict__ zpart,
    const float* __restrict__ bias, const float* __restrict__ g,
    const float* __restrict__ beta, ushort_t* __restrict__ X2,
    float* __restrict__ row0v,
    const float* __restrict__ Wr2, const float* __restrict__ br2,
    float* __restrict__ xr0out) {
    int b = blockIdx.x, t = threadIdx.x;
    __shared__ float vv[96];
    __shared__ float lnS[96];
    __shared__ float red2[2];
    __shared__ float zs[3];
    if (t < 3) {
        long long z = 0;
        for (int s = 0; s < 64; s++) z += zpart[(b * 64 + s) * 4 + t];
        zs[t] = (float)z;
    }
    long long wsum = 0;
    if (t < 96) {
        for (int s = 0; s < 64; s++)
            wsum += w0part[(size_t)(b * 64 + s) * 96 + t];
    }
    __syncthreads();
    float val = 0.f;
    if (t < 96) {
        float wf = (float)wsum;
        float zf = zs[t >> 5];
        val = gelu_f(wf / zf + bias[t]);   // fixed-point scale cancels
        vv[t] = val;
    }
    __syncthreads();
    if (t < 32) {
        float a = vv[t], b2 = vv[t + 32], c = vv[t + 64];
        float s = a + b2 + c, sq = a * a + b2 * b2 + c * c;
#pragma unroll
        for (int mk = 16; mk >= 1; mk >>= 1) { s += __shfl_xor(s, mk, 32); sq += __shfl_xor(sq, mk, 32); }
        if (t == 0) { red2[0] = s; red2[1] = sq; }
    }
    __syncthreads();
    float mean = red2[0] * (1.f / 96.f);
    float var = red2[1] * (1.f / 96.f) - mean * mean;
    float rstd = rsqrtf(var + 1e-5f);
    if (t < 96) {
        float ln = (val - mean) * rstd * g[t] + beta[t];
        if (LAYER == 1) {
            ushort_t lb = f2b(ln);
            X2[(long long)b * NN * 96 + t] = lb;
            lnS[t] = b2f(lb);          // exactly what k_xr0<96> would read
        } else {
            row0v[b * 96 + t] = ln;
        }
    }
    if (LAYER == 1) {
        __syncthreads();
        if (t < 96) {
            float a = br2[t];
            for (int k = 0; k < 96; k++)
                a = fmaf(lnS[k], Wr2[k * 96 + t], a);   // same order as k_xr0
            xr0out[b * 96 + t] = a;
        }
    }
}

// ---------------- final: pool combine (exact integer sums + row-0 term)
// then out = LN(gelu(pooled @ W_out + b_out)) -> [Bc,256]
__global__ __launch_bounds__(256) void k_out(
    const long long* __restrict__ pspart, const long long* __restrict__ pwpart,
    const float* __restrict__ row0v, const float* __restrict__ tptr,
    const float* __restrict__ W, const float* __restrict__ bias,
    const float* __restrict__ g, const float* __restrict__ beta,
    float* __restrict__ out) {
    int b = blockIdx.x, c = threadIdx.x;
    __shared__ float ps[96];
    __shared__ float rs[4], rq[4];
    if (c < 96) {
        long long Si = 0, Wi = 0;
        for (int s = 0; s < 64; s++) {
            Si += pspart[(size_t)(b * 64 + s) * 96 + c];
            Wi += pwpart[(size_t)(b * 64 + s) * 96 + c];
        }
        float ln0 = row0v[b * 96 + c];
        float pe0 = __expf(fminf(tptr[0] * ln0, 24.f));
        float S = (float)Si * INV_SCALE + pe0;
        float Wp = (float)Wi * INV_SCALE + pe0 * ln0;
        ps[c] = Wp / S;
    }
    __syncthreads();
    float acc = bias[c];
    for (int k = 0; k < 96; k++) acc = fmaf(ps[k], W[k * 256 + c], acc);
    float v = gelu_f(acc);
    float s = v, sq = v * v;
#pragma unroll
    for (int mk = 32; mk >= 1; mk >>= 1) { s += __shfl_xor(s, mk, 64); sq += __shfl_xor(sq, mk, 64); }
    if ((c & 63) == 0) { rs[c >> 6] = s; rq[c >> 6] = sq; }
    __syncthreads();
    s = rs[0] + rs[1] + rs[2] + rs[3];
    sq = rq[0] + rq[1] + rq[2] + rq[3];
    float mean = s * (1.f / 256.f);
    float var = sq * (1.f / 256.f) - mean * mean;
    float rstd = rsqrtf(var + 1e-5f);
    out[b * 256 + c] = (v - mean) * rstd * g[c] + beta[c];
}

extern "C" void kernel_launch(void* const* d_in, const int* in_sizes, int n_in,
                              void* d_out, int out_size, void* d_ws, size_t ws_size,
                              hipStream_t stream) {
    const float* in0    = (const float*)d_in[0];
    const float* W_node = (const float*)d_in[1];
    const float* b_node = (const float*)d_in[2];
    const float* lnn_g  = (const float*)d_in[3];
    const float* lnn_b  = (const float*)d_in[4];
    const float* Wl1 = (const float*)d_in[5];
    const float* bl1 = (const float*)d_in[6];
    const float* Wr1 = (const float*)d_in[7];
    const float* br1 = (const float*)d_in[8];
    const float* att1 = (const float*)d_in[9];
    const float* bias1 = (const float*)d_in[10];
    const float* lnc1_g = (const float*)d_in[11];
    const float* lnc1_b = (const float*)d_in[12];
    const float* Wl2 = (const float*)d_in[13];
    const float* bl2 = (const float*)d_in[14];
    const float* Wr2 = (const float*)d_in[15];
    const float* br2 = (const float*)d_in[16];
    const float* att2 = (const float*)d_in[17];
    const float* bias2 = (const float*)d_in[18];
    const float* lnc2_g = (const float*)d_in[19];
    const float* lnc2_b = (const float*)d_in[20];
    const float* tptr = (const float*)d_in[21];
    const float* W_out = (const float*)d_in[22];
    const float* b_out = (const float*)d_in[23];
    const float* lno_g = (const float*)d_in[24];
    const float* lno_b = (const float*)d_in[25];

    auto alignup = [](size_t x) { return (x + 255) & ~(size_t)255; };

    // fixed region: MFMA B-fragments (hi/lo) for both conv layers
    const size_t wf1 = (size_t)6 * 4 * 64 * 8;  // K=128
    const size_t wf2 = (size_t)6 * 3 * 64 * 8;  // K=96
    char* base = (char*)d_ws;
    ushort_t* wf1h = (ushort_t*)base;             base += alignup(wf1 * 2);
    ushort_t* wf1l = (ushort_t*)base;             base += alignup(wf1 * 2);
    ushort_t* wf2h = (ushort_t*)base;             base += alignup(wf2 * 2);
    ushort_t* wf2l = (ushort_t*)base;             base += alignup(wf2 * 2);
    size_t fixed = (size_t)(base - (char*)d_ws);

    // per-chunk: X bf16, X2 bf16, xr0, w0part(i64), zpart(i64), row0v.
    // pool slot arrays (pspart/pwpart, i64) alias the Xbuf region (dead
    // after conv1; 2*slots*96*8 = 12.6 MB << Xbuf 67 MB at bc=128).
    auto need = [&](int bcx) -> size_t {
        size_t rn = (size_t)bcx * NN;
        size_t slots = (size_t)bcx * 64;
        return fixed
             + alignup(rn * 128 * 2)             // X bf16 (holds ps/pw i64 later)
             + alignup(rn * 96 * 2)              // X2 bf16
             + alignup((size_t)bcx * 96 * 4)     // xr0
             + alignup(slots * 96 * 8)           // w0part i64
             + alignup(slots * 4 * 8)            // zpart i64
             + alignup((size_t)bcx * 96 * 4);    // row0v
    };
    int bc = BB;
    while (bc > 1 && need(bc) > ws_size) bc >>= 1;

    k_wprep<128><<<6, 256, 0, stream>>>(Wl1, wf1h, wf1l);
    k_wprep<96><<<5, 256, 0, stream>>>(Wl2, wf2h, wf2l);

    for (int cb = 0; cb < BB; cb += bc) {
        size_t rn = (size_t)bc * NN;
        size_t slots = (size_t)bc * 64;
        char* p = base;
        ushort_t*  Xbuf  = (ushort_t*)p;  p += alignup(rn * 128 * 2);
        ushort_t*  X2buf = (ushort_t*)p;  p += alignup(rn * 96 * 2);
        float*     xr0b  = (float*)p;     p += alignup((size_t)bc * 96 * 4);
        long long* w0pt  = (long long*)p; p += alignup(slots * 96 * 8);
        long long* zpt   = (long long*)p; p += alignup(slots * 4 * 8);
        float*     row0v = (float*)p;
        // pool partials overlay the (dead-after-conv1) Xbuf region
        long long* pspt = (long long*)Xbuf;
        long long* pwpt = pspt + slots * 96;

        const float* inC = in0 + (size_t)cb * NN * FIN;
        float* outC = (float*)d_out + (size_t)cb * 256;

        // stage 1
        k_fcnode<<<bc * NN / 64, 256, 0, stream>>>(inC, W_node, b_node, lnn_g, lnn_b, Xbuf);
        // xr0_1
        k_xr0<128><<<bc, 128, 0, stream>>>(Xbuf, Wr1, br1, xr0b);
        // conv1 (stores Xout; attention partials -> slots), 4-wave blocks
        k_conv<128, false><<<bc * NN / 128, 256, 0, stream>>>(
            Xbuf, wf1h, wf1l, bl1, att1, xr0b, bias1, lnc1_g, lnc1_b,
            w0pt, zpt, X2buf, nullptr, nullptr, nullptr);
        // node-0 finalize (conv1): combine slots, write X2 row 0 + fused xr0_2
        k_row0<1><<<bc, 128, 0, stream>>>(w0pt, zpt, bias1, lnc1_g, lnc1_b,
                                          X2buf, nullptr, Wr2, br2, xr0b);
        // conv2 (attention + pool partials -> slots; Xbuf region now reused)
        k_conv<96, true><<<bc * NN / 128, 256, 0, stream>>>(
            X2buf, wf2h, wf2l, bl2, att2, xr0b, bias2, lnc2_g, lnc2_b,
            w0pt, zpt, nullptr, pspt, pwpt, tptr);
        // node-0 finalize (conv2): combine slots, write row0v
        k_row0<2><<<bc, 128, 0, stream>>>(w0pt, zpt, bias2, lnc2_g, lnc2_b,
                                          nullptr, row0v, nullptr, nullptr, nullptr);
        // pool combine + output head
        k_out<<<bc, 256, 0, stream>>>(pspt, pwpt, row0v, tptr, W_out, b_out,
                                      lno_g, lno_b, outC);
    }
}